// Round 6
// baseline (127.459 us; speedup 1.0000x reference)
//
#include <hip/hip_runtime.h>
#include <hip/hip_bf16.h>

#define N_NODES 100000
#define N_EDGES 1250000
#define D_FEAT  64

// ---- pass 1: coarse buckets of 1024 nodes ----
#define BKW       1024                           // nodes per coarse bucket
#define NB1       98                             // ceil(N_NODES / BKW)
#define SCAP      24                             // LDS staging entries per bucket
#define CHUNK     1024                           // edges per block, pass 1
#define P1T       256
#define BCAP1     13440                          // mean 12800, +5.7 sigma
#define SPILL_CAP 65536

// ---- pass 2: each bucket split 16x -> 64-node tiles ----
#define NW        64                             // nodes per k_acc block
#define SRT_CAP   1280                           // mean 800, +17 sigma

// record = (src << 10) | (dst & 1023)   (src < 2^17 -> 27 bits)
__global__ __launch_bounds__(P1T)
void k_bin(const int* __restrict__ src, const int* __restrict__ dst,
           int* __restrict__ bucket_cnt, unsigned* __restrict__ buckets,
           int* __restrict__ spill_cnt, int* __restrict__ spill) {
    __shared__ int      stg_cnt[NB1];            // 392 B
    __shared__ unsigned stg[NB1][SCAP];          // 9.2 KB
    int tid = threadIdx.x;
    for (int i = tid; i < NB1; i += P1T) stg_cnt[i] = 0;
    __syncthreads();

    int base = blockIdx.x * CHUNK;
    #pragma unroll
    for (int r = 0; r < CHUNK / P1T; ++r) {
        int e = base + r * P1T + tid;
        if (e < N_EDGES) {
            int d = dst[e], s = src[e];
            int b = d >> 10;
            int pos = atomicAdd(&stg_cnt[b], 1);
            unsigned rec = ((unsigned)s << 10) | (unsigned)(d & (BKW - 1));
            if (pos < SCAP) {
                stg[b][pos] = rec;
            } else {                               // staging overflow (very rare)
                int sp = atomicAdd(spill_cnt, 1);
                if (sp < SPILL_CAP) { spill[2 * sp] = d; spill[2 * sp + 1] = s; }
            }
        }
    }
    __syncthreads();

    // drain: one global atomic + ~10-dword contiguous burst per bucket
    for (int b = tid; b < NB1; b += P1T) {
        int cnt = stg_cnt[b];
        if (cnt > SCAP) cnt = SCAP;
        if (cnt > 0) {
            int gbase = atomicAdd(&bucket_cnt[b], cnt);
            for (int k = 0; k < cnt; ++k) {
                int gp = gbase + k;
                unsigned rec = stg[b][k];
                if (gp < BCAP1) {
                    buckets[(long long)b * BCAP1 + gp] = rec;
                } else {                           // bucket overflow (very rare)
                    int sp = atomicAdd(spill_cnt, 1);
                    if (sp < SPILL_CAP) {
                        spill[2 * sp]     = b * BKW + (int)(rec & (BKW - 1));
                        spill[2 * sp + 1] = (int)(rec >> 10);
                    }
                }
            }
        }
    }
}

// pass 2: one block per 64-node tile. Filter bucket records (bits 6..9 select
// the tile), counting-sort into LDS by dst_low6, then float4 register gather:
// 16 lanes per row -> one wave loads 4 edge rows per instruction.
__global__ __launch_bounds__(256)
void k_acc(const float* __restrict__ x, const int* __restrict__ bucket_cnt,
           const unsigned* __restrict__ buckets, float* __restrict__ out) {
    __shared__ unsigned srt[SRT_CAP];            // 5 KB: src ids sorted by dst_low6
    __shared__ int hist[NW];
    __shared__ int offs[NW + 1];
    __shared__ int scan_tmp[NW];
    int tid = threadIdx.x;
    int b1 = blockIdx.x >> 4;                    // coarse bucket
    int h  = blockIdx.x & 15;                    // 64-node tile within bucket
    int cnt = bucket_cnt[b1];
    if (cnt > BCAP1) cnt = BCAP1;
    const unsigned* bk = buckets + (long long)b1 * BCAP1;

    if (tid < NW) hist[tid] = 0;
    __syncthreads();

    // filtered histogram (~800 matching of ~12800)
    for (int k = tid; k < cnt; k += 256) {
        unsigned rec = bk[k];
        if (((rec >> 6) & 15) == (unsigned)h)
            atomicAdd(&hist[rec & (NW - 1)], 1);
    }
    __syncthreads();

    // Hillis-Steele inclusive scan over 64 counters
    if (tid < NW) scan_tmp[tid] = hist[tid];
    __syncthreads();
    for (int d = 1; d < NW; d <<= 1) {
        int v = 0;
        if (tid < NW && tid >= d) v = scan_tmp[tid - d];
        __syncthreads();
        if (tid < NW && tid >= d) scan_tmp[tid] += v;
        __syncthreads();
    }
    if (tid < NW) {
        offs[tid + 1] = scan_tmp[tid] < SRT_CAP ? scan_tmp[tid] : SRT_CAP;
        if (tid == 0) offs[0] = 0;
        hist[tid] = 0;                           // reuse as scatter cursor
    }
    __syncthreads();

    // scatter matching records into per-node sorted order (store src id)
    for (int k = tid; k < cnt; k += 256) {
        unsigned rec = bk[k];
        if (((rec >> 6) & 15) == (unsigned)h) {
            int d6 = rec & (NW - 1);
            int pos = atomicAdd(&hist[d6], 1);
            int idx = offs[d6] + pos;
            if (idx < SRT_CAP) srt[idx] = rec >> 10;
        }
    }
    __syncthreads();

    // register gather: wave handles a node; 16 lanes x float4 = one 256B row,
    // 4 sub-groups process 4 edges per load instruction.
    int wid = tid >> 6, lane = tid & 63;
    int sub = lane >> 4, fl = lane & 15;
    long long nbase = (long long)b1 * BKW + (long long)h * NW;
    for (int n = wid; n < NW; n += 4) {
        long long node = nbase + n;
        if (node >= N_NODES) break;              // wave-uniform
        int k0 = offs[n], k1 = offs[n + 1];
        float4 a0 = make_float4(0.f, 0.f, 0.f, 0.f);
        float4 a1 = make_float4(0.f, 0.f, 0.f, 0.f);
        int k = k0 + sub;
        for (; k + 4 < k1; k += 8) {             // 2-way unroll -> 2KB in flight
            const float4 v0 = *(const float4*)&x[(long long)srt[k]     * D_FEAT + fl * 4];
            const float4 v1 = *(const float4*)&x[(long long)srt[k + 4] * D_FEAT + fl * 4];
            a0.x += v0.x; a0.y += v0.y; a0.z += v0.z; a0.w += v0.w;
            a1.x += v1.x; a1.y += v1.y; a1.z += v1.z; a1.w += v1.w;
        }
        if (k < k1) {
            const float4 v0 = *(const float4*)&x[(long long)srt[k] * D_FEAT + fl * 4];
            a0.x += v0.x; a0.y += v0.y; a0.z += v0.z; a0.w += v0.w;
        }
        a0.x += a1.x; a0.y += a1.y; a0.z += a1.z; a0.w += a1.w;
        // butterfly-reduce the 4 sub-groups (xor 16, then 32)
        a0.x += __shfl_xor(a0.x, 16, 64); a0.y += __shfl_xor(a0.y, 16, 64);
        a0.z += __shfl_xor(a0.z, 16, 64); a0.w += __shfl_xor(a0.w, 16, 64);
        a0.x += __shfl_xor(a0.x, 32, 64); a0.y += __shfl_xor(a0.y, 32, 64);
        a0.z += __shfl_xor(a0.z, 32, 64); a0.w += __shfl_xor(a0.w, 32, 64);
        if (sub == 0)
            *(float4*)&out[node * D_FEAT + fl * 4] = a0;
    }
}

// pass 3: rare spilled edges via atomics (after k_acc's overwriting stores)
__global__ __launch_bounds__(256)
void k_spill(const float* __restrict__ x, const int* __restrict__ spill_cnt,
             const int* __restrict__ spill, float* __restrict__ out) {
    int sc = *spill_cnt;
    if (sc > SPILL_CAP) sc = SPILL_CAP;
    int total = sc * D_FEAT;
    int stride = gridDim.x * blockDim.x;
    for (int i = blockIdx.x * blockDim.x + threadIdx.x; i < total; i += stride) {
        int p = i >> 6, f = i & 63;
        int d = spill[2 * p], s = spill[2 * p + 1];
        atomicAdd(&out[(long long)d * D_FEAT + f], x[(long long)s * D_FEAT + f]);
    }
}

// fallback: direct atomic scatter
__global__ __launch_bounds__(256)
void mp_scatter_atomic(const float* __restrict__ x,
                       const int* __restrict__ src,
                       const int* __restrict__ dst,
                       float* __restrict__ out) {
    long long t = (long long)blockIdx.x * blockDim.x + threadIdx.x;
    long long e = t >> 6;
    int f = (int)(t & 63);
    if (e >= N_EDGES) return;
    atomicAdd(&out[(long long)dst[e] * D_FEAT + f],
              x[(long long)src[e] * D_FEAT + f]);
}

extern "C" void kernel_launch(void* const* d_in, const int* in_sizes, int n_in,
                              void* d_out, int out_size, void* d_ws, size_t ws_size,
                              hipStream_t stream) {
    const float* x   = (const float*)d_in[0];
    const int*   ei  = (const int*)d_in[1];   // (2, N_EDGES): row 0 = src, row 1 = dst
    const int*   src = ei;
    const int*   dst = ei + N_EDGES;
    float* out = (float*)d_out;

    // ws layout (ints): bucket_cnt[NB1] | spill_cnt[1] | spill[2*SPILL_CAP] | (align) | buckets[NB1*BCAP1]
    const size_t BK_OFF   = ((size_t)NB1 + 1 + 2 * SPILL_CAP + 63) & ~(size_t)63;
    const size_t WS_INTS  = BK_OFF + (size_t)NB1 * BCAP1;
    const size_t WS_BYTES = WS_INTS * sizeof(int);   // ~5.8 MB

    if (ws_size >= WS_BYTES) {
        int*      wsi        = (int*)d_ws;
        int*      bucket_cnt = wsi;
        int*      spill_cnt  = wsi + NB1;
        int*      spill      = wsi + NB1 + 1;
        unsigned* buckets    = (unsigned*)(wsi + BK_OFF);

        (void)hipMemsetAsync(bucket_cnt, 0, (size_t)(NB1 + 1) * sizeof(int), stream);

        int grid_bin = (N_EDGES + CHUNK - 1) / CHUNK;     // 1221
        k_bin<<<grid_bin, P1T, 0, stream>>>(src, dst, bucket_cnt, buckets,
                                            spill_cnt, spill);

        k_acc<<<NB1 * 16, 256, 0, stream>>>(x, bucket_cnt, buckets, out);

        k_spill<<<32, 256, 0, stream>>>(x, spill_cnt, spill, out);
    } else {
        (void)hipMemsetAsync(out, 0, (size_t)out_size * sizeof(float), stream);
        long long total = (long long)N_EDGES * D_FEAT;
        int block = 256;
        long long grid = (total + block - 1) / block;
        mp_scatter_atomic<<<(dim3)(unsigned)grid, block, 0, stream>>>(x, src, dst, out);
    }
}